// Round 3
// baseline (247.467 us; speedup 1.0000x reference)
//
#include <hip/hip_runtime.h>

#define DIM 4096
#define HAD_SCALE 0.015625f  // 1/sqrt(4096) = 1/64

// Float-index XOR swizzle: injects j bits {8,9,10} into bank bits {2,3,4}.
// Bijective; preserves 16B groups (bits 0-1 untouched; mask depends on
// bits >= 8 only, which are fixed within any float4 group).
__device__ __forceinline__ int swz(int a) {
    return a ^ (((a >> 8) & 7) << 2);
}

// In-register FWHT-64 over r[0..63]; index bit s of i is one transform bit.
// Lower-index element gets a+b (matches reference orientation per bit).
__device__ __forceinline__ void fwht64(float* r) {
#pragma unroll
    for (int s = 1; s < 64; s <<= 1) {
#pragma unroll
        for (int i = 0; i < 64; i++) {
            if ((i & s) == 0) {
                float a = r[i];
                float b = r[i ^ s];
                r[i]     = a + b;
                r[i ^ s] = a - b;
            }
        }
    }
}

// One WAVE (64-thread block) per 4096-float row; 64 floats/lane.
// Radix-64 x radix-64 decomposition, ONE LDS transpose, ZERO cross-wave
// barriers -> no phase-locking, pipes overlap across the ~10 resident
// waves/CU (LDS-capped: 16 KiB/block).
//
// Load layout:  j = e + 4*L + 256*c   (e=j[1:0] in float4, c=j[11:8] in reg,
//                                      L=j[7:2] = lane)
// Phase 1: FWHT-64 over in-register index i = e + 4*c -> transforms
//          j bits {0,1,8,9,10,11}.
// Transpose: LDS at swz(j). Writes are b128 (1 KiB/instr, full throughput);
//          reads are stride-4 b32, swizzle makes them 2 lanes/bank (free).
// Phase 2: lane M owns j = (M&3) + 4*v + 256*(M>>2), v=0..63 in-register;
//          FWHT-64 over v -> transforms j bits {2..7}. Scale, store.
__global__ __launch_bounds__(64, 4) void fwht_kernel(const float* __restrict__ x,
                                                     float* __restrict__ y) {
    __shared__ float lds[DIM];  // 16 KiB, wave-private (single-wave block)
    const int L = threadIdx.x;  // lane 0..63
    const size_t row = blockIdx.x;
    const float* xin = x + row * DIM;
    float* yout = y + row * DIM;

    float4 r4[16];
    float* r = (float*)r4;

    // ---- 16 coalesced dwordx4 loads (1 KiB per wave-instruction), all
    // issued before any use: 16 KiB in flight per wave.
    const float4* __restrict__ x4 = (const float4*)xin;
#pragma unroll
    for (int c = 0; c < 16; c++) r4[c] = x4[c * 64 + L];

    // ---- Phase 1a: FWHT-4 within each float4 (bits {0,1}); consumes loads
    // in arrival order so the compiler can emit decreasing vmcnt waits.
#pragma unroll
    for (int c = 0; c < 16; c++) {
        float a0 = r[4 * c + 0], a1 = r[4 * c + 1];
        float a2 = r[4 * c + 2], a3 = r[4 * c + 3];
        float b0 = a0 + a1, b1 = a0 - a1, b2 = a2 + a3, b3 = a2 - a3;
        r[4 * c + 0] = b0 + b2;
        r[4 * c + 1] = b1 + b3;
        r[4 * c + 2] = b0 - b2;
        r[4 * c + 3] = b1 - b3;
    }
    // ---- Phase 1b: remaining 4 stages over c = i>>2 (bits {8..11}).
#pragma unroll
    for (int s = 4; s < 64; s <<= 1) {
#pragma unroll
        for (int i = 0; i < 64; i++) {
            if ((i & s) == 0) {
                float a = r[i];
                float b = r[i ^ s];
                r[i]     = a + b;
                r[i ^ s] = a - b;
            }
        }
    }

    // ---- Transpose write: b128 at swz(e + 4L + 256c). Per instruction the
    // wave writes a permuted-but-complete 1 KiB region: full LDS throughput.
#pragma unroll
    for (int c = 0; c < 16; c++) {
        *(float4*)&lds[swz(4 * L + 256 * c)] = r4[c];
    }
    __syncthreads();  // single-wave block: compiles to a cheap waitcnt+barrier;
                      // vmcnt already drained by data deps (loads consumed).

    // ---- Transpose read: lane M=(e,k) gathers v=0..63.
    // bank = e + 4*((v^k)&7) -> exactly 2 lanes/bank (free on gfx950).
    const int e = L & 3;
    const int k = L >> 2;
    const int base = e + (k << 8);
#pragma unroll
    for (int v = 0; v < 64; v++) r[v] = lds[swz(base + (v << 2))];

    // ---- Phase 2: FWHT-64 over v (bits {2..7}).
    fwht64(r);

    // ---- Scaled store: instr v writes 16 chunks of 16 B (e-lanes
    // contiguous, k-lanes 1 KiB apart); consecutive v fill each 128 B line
    // within the same wave -> L2 merges, WRITE_SIZE stays exact.
#pragma unroll
    for (int v = 0; v < 64; v++) {
        yout[base + (v << 2)] = r[v] * HAD_SCALE;
    }
}

extern "C" void kernel_launch(void* const* d_in, const int* in_sizes, int n_in,
                              void* d_out, int out_size, void* d_ws, size_t ws_size,
                              hipStream_t stream) {
    const float* x = (const float*)d_in[0];
    float* y = (float*)d_out;
    const int n = in_sizes[0];
    const int rows = n / DIM;  // 8192 for (4, 2048, 4096)
    fwht_kernel<<<rows, 64, 0, stream>>>(x, y);
}